// Round 15
// baseline (38978.668 us; speedup 1.0000x reference)
//
#include <hip/hip_runtime.h>
#include <math.h>

typedef __bf16 bf16x8 __attribute__((ext_vector_type(8)));
typedef float  f32x4  __attribute__((ext_vector_type(4)));
typedef _Float16 f16x2 __attribute__((ext_vector_type(2)));

__device__ __forceinline__ ushort f2bf(float f) {
  union { float f; unsigned u; } v; v.f = f;
  unsigned r = v.u + 0x7FFFu + ((v.u >> 16) & 1u);
  return (ushort)(r >> 16);
}
__device__ __forceinline__ float bf2f(ushort s) {
  union { unsigned u; float f; } v; v.u = ((unsigned)s) << 16;
  return v.f;
}
__device__ __forceinline__ unsigned pkrtz(float a, float b) {
  return __builtin_bit_cast(unsigned, __builtin_amdgcn_cvt_pkrtz(a, b));
}
__device__ __forceinline__ float fdot2(unsigned a, unsigned b, float c) {
  return __builtin_amdgcn_fdot2(__builtin_bit_cast(f16x2, a),
                                __builtin_bit_cast(f16x2, b), c, false);
}

__device__ __forceinline__ void gload_lds16(const ushort* g, ushort* l) {
  __builtin_amdgcn_global_load_lds((const __attribute__((address_space(1))) void*)g,
                                   (__attribute__((address_space(3))) void*)l, 16, 0, 0);
}

// fast GELU: h * sigmoid(1.5957691*h*(1+0.044715*h^2)), sigmoid via v_rcp
__device__ __forceinline__ float gelu_fast(float h) {
  float y = 1.5957691216057308f * h * (1.f + 0.044715f * h * h);
  return h * __builtin_amdgcn_rcpf(1.f + __expf(-y));
}

// ---------------- all 4 weight transposes in one launch ----------------
__global__ void wtrans_all(const float* __restrict__ W0, ushort* __restrict__ T0,
                           const float* __restrict__ W1, ushort* __restrict__ T1,
                           const float* __restrict__ W2, ushort* __restrict__ T2,
                           const float* __restrict__ W3, ushort* __restrict__ T3) {
  int idx = blockIdx.x * 256 + threadIdx.x;
  const float* W; ushort* T; int K, N, rel;
  if (idx < 442368)        { W = W0; T = T0; K = 384;  N = 1152; rel = idx; }
  else if (idx < 589824)   { W = W1; T = T1; K = 384;  N = 384;  rel = idx - 442368; }
  else if (idx < 1179648)  { W = W2; T = T2; K = 384;  N = 1536; rel = idx - 589824; }
  else                     { W = W3; T = T3; K = 1536; N = 384;  rel = idx - 1179648; }
  int n = rel / K, k = rel - n * K;
  T[rel] = f2bf(W[(size_t)k * N + n]);
}

// ---------------- LayerNorm (one wave per row of 384), paired loads/stores ----------------
template<bool SHIFT, bool INBF16>
__global__ __launch_bounds__(256) void ln_kernel(const void* __restrict__ inp,
                                                 ushort* __restrict__ outp,
                                                 const float* __restrict__ gamma,
                                                 const float* __restrict__ beta) {
  const int lane = threadIdx.x & 63;
  const int row = blockIdx.x * 4 + (threadIdx.x >> 6);
  size_t src;
  if (SHIFT) {
    int b = row / 3136, rem = row - b * 3136;
    int win = rem / 49, n = rem - win * 49;
    int wh = win >> 3, ww = win & 7;
    int i = n / 7, j = n - (n / 7) * 7;
    int h = wh * 7 + i + 3; if (h >= 56) h -= 56;
    int w = ww * 7 + j + 3; if (w >= 56) w -= 56;
    src = ((size_t)b * 3136 + h * 56 + w) * 384;
  } else {
    src = (size_t)row * 384;
  }
  float2 xv[3];
  float sum = 0.f, sq = 0.f;
#pragma unroll
  for (int t = 0; t < 3; t++) {
    int c = (lane + t * 64) * 2;
    float2 f;
    if (INBF16) {
      unsigned u = *(const unsigned*)((const ushort*)inp + src + c);
      f.x = bf2f((ushort)(u & 0xFFFF));
      f.y = bf2f((ushort)(u >> 16));
    } else {
      f = *(const float2*)((const float*)inp + src + c);
    }
    xv[t] = f; sum += f.x + f.y; sq += f.x * f.x + f.y * f.y;
  }
#pragma unroll
  for (int o = 32; o; o >>= 1) { sum += __shfl_xor(sum, o); sq += __shfl_xor(sq, o); }
  float mean = sum * (1.f / 384.f);
  float var  = sq * (1.f / 384.f) - mean * mean;
  float inv  = rsqrtf(var + 1e-5f);
#pragma unroll
  for (int t = 0; t < 3; t++) {
    int c = (lane + t * 64) * 2;
    float2 g = *(const float2*)(gamma + c);
    float2 b = *(const float2*)(beta + c);
    ushort2 o;
    o.x = f2bf((xv[t].x - mean) * inv * g.x + b.x);
    o.y = f2bf((xv[t].y - mean) * inv * g.y + b.y);
    *(ushort2*)(outp + (size_t)row * 384 + c) = o;
  }
}

#define EPI_QKV  0
#define EPI_PROJ 1
#define EPI_MLP1 2
#define EPI_MLP2 3

// ---------------- pipelined GEMM: 128x128 block, 8 waves x 64x32, BK=32 ----------------
// 4-buffer LDS (64KB, 2 blocks/CU), D=3 staging with counted vmcnt(2), register
// double-buffered fragments (prefetch iter t+1's frags during iter t's MFMA -> the
// MFMA cluster never waits on fresh ds_reads). XOR-swizzle key (row>>1)&3.
template<int EPI>
__global__ __launch_bounds__(512, 4) void gemmp_kernel(
    const ushort* __restrict__ A, const ushort* __restrict__ BT,
    const float* __restrict__ bias, void* __restrict__ Cout,
    const void* __restrict__ extra, int M, int N, int K, int nbn, int cpx) {
  __shared__ ushort SH[32768];   // A: 4x4096, B (at 16384): 4x4096; epi scratch reuse
  const int tid = threadIdx.x;
  const int flat = blockIdx.x;
  const int wg = (flat & 7) * cpx + (flat >> 3);   // bijective XCD swizzle (nwg%8==0)
  const int bm = wg / nbn, bn = wg - bm * nbn;
  const int m0 = bm * 128, n0 = bn * 128;
  const int lane = tid & 63, wave = tid >> 6;      // 8 waves
  const int wr = (wave >> 2) * 64, wc = (wave & 3) * 32;
  const int fr = lane & 15, fq = lane >> 4;
  const int key = (fr >> 1) & 3;
  f32x4 acc[4][2] = {};

  const int r8 = lane >> 2;                        // row 0..15 within 16-row chunk
  const int sslot = ((lane & 3) ^ ((lane >> 3) & 3)) * 8;
  const size_t a_base = (size_t)(m0 + wave * 16 + r8) * K + sslot;
  const size_t b_base = (size_t)(n0 + wave * 16 + r8) * K + sslot;

#define STAGE(c, kt_) do {                                         \
    gload_lds16(A  + a_base + (kt_), SH + (c) * 4096 + wave * 512);           \
    gload_lds16(BT + b_base + (kt_), SH + 16384 + (c) * 4096 + wave * 512);   \
  } while (0)

#define LOADF(s, c) do {                                           \
    _Pragma("unroll")                                              \
    for (int i = 0; i < 4; i++) {                                  \
      int ra = wr + i * 16 + fr;                                   \
      fa[s][i] = *(const bf16x8*)&SH[(c) * 4096 + ra * 32 + ((fq ^ key) * 8)]; \
    }                                                              \
    _Pragma("unroll")                                              \
    for (int j = 0; j < 2; j++) {                                  \
      int rb = wc + j * 16 + fr;                                   \
      fb[s][j] = *(const bf16x8*)&SH[16384 + (c) * 4096 + rb * 32 + ((fq ^ key) * 8)]; \
    }                                                              \
  } while (0)

  const int NT = K >> 5;   // 12 (K=384) or 48 (K=1536), always even and >= 4
  STAGE(0, 0);
  STAGE(1, 32);
  STAGE(2, 64);
  asm volatile("s_waitcnt vmcnt(2) lgkmcnt(0)" ::: "memory");
  __builtin_amdgcn_s_barrier();
  __builtin_amdgcn_sched_barrier(0);

  bf16x8 fa[2][4], fb[2][2];
  LOADF(0, 0);
#pragma unroll 2
  for (int t = 0; t < NT; ++t) {
    const int cur = t & 1;
    if (t + 3 < NT) STAGE((t + 3) & 3, (t + 3) * 32);
    if (t + 1 < NT) {
      const int nb = (t + 1) & 3;
      if (cur == 0) LOADF(1, nb); else LOADF(0, nb);
    }
    __builtin_amdgcn_sched_barrier(0);
    __builtin_amdgcn_s_setprio(1);
#pragma unroll
    for (int i = 0; i < 4; i++)
#pragma unroll
      for (int j = 0; j < 2; j++)
        acc[i][j] = __builtin_amdgcn_mfma_f32_16x16x32_bf16(fa[cur][i], fb[cur][j], acc[i][j], 0, 0, 0);
    __builtin_amdgcn_s_setprio(0);
    if (t + 1 < NT) {
      asm volatile("s_waitcnt vmcnt(2)" ::: "memory");
      __builtin_amdgcn_s_barrier();
      __builtin_amdgcn_sched_barrier(0);
    }
  }
#undef STAGE
#undef LOADF

  __syncthreads();
  float biasv[2];
#pragma unroll
  for (int j = 0; j < 2; j++) biasv[j] = bias[n0 + wc + j * 16 + fr];

  if constexpr (EPI == EPI_MLP2) {
    float* scr = (float*)SH + wave * 1152;
#pragma unroll
    for (int c = 0; c < 2; c++) {
#pragma unroll
      for (int i = 0; i < 2; i++)
#pragma unroll
        for (int j = 0; j < 2; j++)
#pragma unroll
          for (int r = 0; r < 4; r++)
            scr[(i * 16 + fq * 4 + r) * 36 + j * 16 + fr] = acc[c * 2 + i][j][r] + biasv[j];
      asm volatile("" ::: "memory");
#pragma unroll
      for (int it = 0; it < 4; it++) {
        int row = it * 8 + (lane >> 3);
        f32x4 v = *(const f32x4*)&scr[row * 36 + (lane & 7) * 4];
        int m = m0 + wr + c * 32 + row;
        int col0 = n0 + wc + (lane & 7) * 4;
        ushort4 xv = *(const ushort4*)((const ushort*)extra + (size_t)m * N + col0);
        v[0] += bf2f(xv.x); v[1] += bf2f(xv.y); v[2] += bf2f(xv.z); v[3] += bf2f(xv.w);
        *(f32x4*)((float*)Cout + (size_t)m * N + col0) = v;
      }
      asm volatile("" ::: "memory");
    }
  } else {
    ushort* scr = SH + wave * 2304;
#pragma unroll
    for (int i = 0; i < 4; i++)
#pragma unroll
      for (int j = 0; j < 2; j++)
#pragma unroll
        for (int r = 0; r < 4; r++) {
          float val = acc[i][j][r] + biasv[j];
          if constexpr (EPI == EPI_MLP1) val = gelu_fast(val);
          scr[(i * 16 + fq * 4 + r) * 36 + j * 16 + fr] = f2bf(val);
        }
    asm volatile("" ::: "memory");
#pragma unroll
    for (int it = 0; it < 4; it++) {
      int row = it * 16 + (lane >> 2);
      int m = m0 + wr + row;
      int col0 = n0 + wc + (lane & 3) * 8;
      ushort v[8];
      *(bf16x8*)v = *(const bf16x8*)&scr[row * 36 + (lane & 3) * 8];
      if constexpr (EPI == EPI_PROJ) {
        int b_ = m / 3136, rem = m - b_ * 3136;
        int win = rem / 49, nn = rem - win * 49;
        int wh = win >> 3, ww = win & 7;
        int ii = nn / 7, jj = nn - (nn / 7) * 7;
        int h = wh * 7 + ii + 3; if (h >= 56) h -= 56;
        int w = ww * 7 + jj + 3; if (w >= 56) w -= 56;
        size_t rowbase = ((size_t)b_ * 3136 + h * 56 + w) * 384;
        const float* e = (const float*)extra + rowbase + col0;
        ushort o[8];
#pragma unroll
        for (int k = 0; k < 8; k++) o[k] = f2bf(bf2f(v[k]) + e[k]);
        *(bf16x8*)((ushort*)Cout + rowbase + col0) = *(bf16x8*)o;
      } else {
        *(bf16x8*)((ushort*)Cout + (size_t)m * N + col0) = *(bf16x8*)v;
      }
    }
  }
}

// ---------------- windowed attention: streaming softmax, f16 dot2 math ----------------
__global__ __launch_bounds__(128) void attn_kernel(
    const ushort* __restrict__ qkv, const float* __restrict__ bias_table,
    ushort* __restrict__ outp) {
  __shared__ unsigned k_lds[2][49][16];
  __shared__ unsigned v_lds[2][32][28];
  __shared__ float btab[2][169];
  __shared__ char  rgn[2][52];
  const int wave = threadIdx.x >> 6, lane = threadIdx.x & 63;
  const int gw = blockIdx.x * 2 + wave;
  const int bw = gw / 12, head = gw - bw * 12;
  const ushort* base = qkv + (size_t)bw * 49 * 1152 + head * 32;

  for (int t = lane; t < 392; t += 64) {
    int m = t >> 3, c4 = t & 7;
    ushort4 u = *(const ushort4*)(base + (size_t)m * 1152 + 384 + c4 * 4);
    *(uint2*)&k_lds[wave][m][c4 * 2] =
        make_uint2(pkrtz(bf2f(u.x), bf2f(u.y)), pkrtz(bf2f(u.z), bf2f(u.w)));
  }
  for (int t = lane; t < 224; t += 64) {
    int m2 = t >> 3, c4 = t & 7;
    float4 f0 = make_float4(0.f, 0.f, 0.f, 0.f), f1 = f0;
    if (m2 <= 24) {
      ushort4 u = *(const ushort4*)(base + (size_t)(2 * m2) * 1152 + 768 + c4 * 4);
      f0 = make_float4(bf2f(u.x), bf2f(u.y), bf2f(u.z), bf2f(u.w));
    }
    if (m2 <= 23) {
      ushort4 u = *(const ushort4*)(base + (size_t)(2 * m2 + 1) * 1152 + 768 + c4 * 4);
      f1 = make_float4(bf2f(u.x), bf2f(u.y), bf2f(u.z), bf2f(u.w));
    }
    v_lds[wave][c4 * 4 + 0][m2] = pkrtz(f0.x, f1.x);
    v_lds[wave][c4 * 4 + 1][m2] = pkrtz(f0.y, f1.y);
    v_lds[wave][c4 * 4 + 2][m2] = pkrtz(f0.z, f1.z);
    v_lds[wave][c4 * 4 + 3][m2] = pkrtz(f0.w, f1.w);
  }
  for (int t = lane; t < 169; t += 64) btab[wave][t] = bias_table[t * 12 + head];
  {
    int win = bw & 63, wh = win >> 3, ww = win & 7;
    if (lane < 49) {
      int i = lane / 7, j = lane - (lane / 7) * 7;
      int hs = wh * 7 + i, wsf = ww * 7 + j;
      int bh = (hs < 49) ? 0 : (hs < 53 ? 1 : 2);
      int bv = (wsf < 49) ? 0 : (wsf < 53 ? 1 : 2);
      rgn[wave][lane] = (char)(bh * 3 + bv);
    }
  }
  __syncthreads();

  const int n = (lane < 49) ? lane : 48;
  unsigned q2[16];
  {
    const ushort* qp = base + (size_t)n * 1152;
#pragma unroll
    for (int t = 0; t < 8; t++) {
      ushort4 u = *(const ushort4*)(qp + t * 4);
      const float sc = 0.17677669529663689f;
      q2[2 * t]     = pkrtz(bf2f(u.x) * sc, bf2f(u.y) * sc);
      q2[2 * t + 1] = pkrtz(bf2f(u.z) * sc, bf2f(u.w) * sc);
    }
  }
  const char rn = rgn[wave][n];
  const int i_n = n / 7, j_n = n - (n / 7) * 7;
  const float* bt = &btab[wave][(i_n + 6) * 13 + (j_n + 6)];

  auto qk_one = [&](int m) -> float {
    const uint4* kr = (const uint4*)&k_lds[wave][m][0];
    uint4 k0 = kr[0], k1 = kr[1], k2 = kr[2], k3 = kr[3];
    float a0 = 0.f, a1 = 0.f, a2 = 0.f, a3 = 0.f;
    a0 = fdot2(k0.x, q2[0],  a0); a1 = fdot2(k0.y, q2[1],  a1);
    a2 = fdot2(k0.z, q2[2],  a2); a3 = fdot2(k0.w, q2[3],  a3);
    a0 = fdot2(k1.x, q2[4],  a0); a1 = fdot2(k1.y, q2[5],  a1);
    a2 = fdot2(k1.z, q2[6],  a2); a3 = fdot2(k1.w, q2[7],  a3);
    a0 = fdot2(k2.x, q2[8],  a0); a1 = fdot2(k2.y, q2[9],  a1);
    a2 = fdot2(k2.z, q2[10], a2); a3 = fdot2(k2.w, q2[11], a3);
    a0 = fdot2(k3.x, q2[12], a0); a1 = fdot2(k3.y, q2[13], a1);
    a2 = fdot2(k3.z, q2[14], a2); a3 = fdot2(k3.w, q2[15], a3);
    int im = m / 7, jm = m - (m / 7) * 7;
    float s = (a0 + a1) + (a2 + a3) + bt[-im * 13 - jm];
    s += (rgn[wave][m] == rn) ? 0.f : -100.f;
    return __expf(s);
  };

  float sum = 0.f;
  unsigned p2[28];
#pragma unroll
  for (int m2 = 0; m2 < 25; m2++) {
    float eA = qk_one(2 * m2);
    float eB = (m2 < 24) ? qk_one(2 * m2 + 1) : 0.f;
    sum += eA + eB;
    p2[m2] = pkrtz(eA, eB);
  }
  p2[25] = 0; p2[26] = 0; p2[27] = 0;

  const float invs = __builtin_amdgcn_rcpf(sum);
  ushort* op = outp + (size_t)(bw * 49 + n) * 384 + head * 32;
#pragma unroll
  for (int dc = 0; dc < 4; dc++) {
    ushort u8[8];
#pragma unroll
    for (int j = 0; j < 8; j++) {
      const uint4* vr = (const uint4*)&v_lds[wave][dc * 8 + j][0];
      float a0 = 0.f, a1 = 0.f, a2 = 0.f, a3 = 0.f;
#pragma unroll
      for (int t7 = 0; t7 < 7; t7++) {
        uint4 vv = vr[t7];
        a0 = fdot2(vv.x, p2[t7 * 4 + 0], a0);
        a1 = fdot2(vv.y, p2[t7 * 4 + 1], a1);
        a2 = fdot2(vv.z, p2[t7 * 4 + 2], a2);
        a3 = fdot2(vv.w, p2[t7 * 4 + 3], a3);
      }
      u8[j] = f2bf(((a0 + a1) + (a2 + a3)) * invs);
    }
    if (lane < 49) *(bf16x8*)(op + dc * 8) = *(bf16x8*)u8;
  }
}

extern "C" void kernel_launch(void* const* d_in, const int* in_sizes, int n_in,
                              void* d_out, int out_size, void* d_ws, size_t ws_size,
                              hipStream_t stream) {
  (void)in_sizes; (void)n_in; (void)out_size; (void)ws_size;
  const float* x      = (const float*)d_in[0];
  const float* W_qkv  = (const float*)d_in[1];
  const float* b_qkv  = (const float*)d_in[2];
  const float* W_proj = (const float*)d_in[3];
  const float* b_proj = (const float*)d_in[4];
  const float* btab   = (const float*)d_in[5];
  const float* gamma1 = (const float*)d_in[6];
  const float* beta1  = (const float*)d_in[7];
  const float* gamma2 = (const float*)d_in[8];
  const float* beta2  = (const float*)d_in[9];
  const float* W_mlp1 = (const float*)d_in[10];
  const float* b_mlp1 = (const float*)d_in[11];
  const float* W_mlp2 = (const float*)d_in[12];
  const float* b_mlp2 = (const float*)d_in[13];

  const int M = 100352;  // 32 * 3136 token rows

  char* ws = (char*)d_ws;
  ushort* WqkvT  = (ushort*)ws; ws += (size_t)1152 * 384 * 2;
  ushort* WprojT = (ushort*)ws; ws += (size_t)384 * 384 * 2;
  ushort* Wm1T   = (ushort*)ws; ws += (size_t)1536 * 384 * 2;
  ushort* Wm2T   = (ushort*)ws; ws += (size_t)384 * 1536 * 2;
  ushort* x1     = (ushort*)ws; ws += (size_t)M * 384 * 2;   // bf16 residual trunk
  ushort* h2     = (ushort*)ws; ws += (size_t)M * 384 * 2;
  ushort* bufB   = (ushort*)ws;                               // overlay region
  ushort* xw     = bufB;                                      // [M][384]
  ushort* qkv    = bufB + (size_t)M * 384;                    // [M][1152]
  ushort* attn_o = bufB;                                      // [M][384]  (over xw)
  ushort* g      = bufB;                                      // [M][1536] (over all)

  wtrans_all<<<6912, 256, 0, stream>>>(W_qkv, WqkvT, W_proj, WprojT,
                                       W_mlp1, Wm1T, W_mlp2, Wm2T);

  ln_kernel<true,  false><<<M / 4, 256, 0, stream>>>(x, xw, gamma1, beta1);

  {
    int nbn = 1152 / 128, nwg = (M / 128) * nbn;
    gemmp_kernel<EPI_QKV ><<<nwg, 512, 0, stream>>>(xw, WqkvT, b_qkv, qkv, nullptr, M, 1152, 384, nbn, nwg / 8);
  }
  attn_kernel<<<12288, 128, 0, stream>>>(qkv, btab, attn_o);
  {
    int nbn = 384 / 128, nwg = (M / 128) * nbn;
    gemmp_kernel<EPI_PROJ><<<nwg, 512, 0, stream>>>(attn_o, WprojT, b_proj, x1, x, M, 384, 384, nbn, nwg / 8);
  }
  ln_kernel<false, true><<<M / 4, 256, 0, stream>>>(x1, h2, gamma2, beta2);
  {
    int nbn = 1536 / 128, nwg = (M / 128) * nbn;
    gemmp_kernel<EPI_MLP1><<<nwg, 512, 0, stream>>>(h2, Wm1T, b_mlp1, g, nullptr, M, 1536, 384, nbn, nwg / 8);
  }
  {
    int nbn = 384 / 128, nwg = (M / 128) * nbn;
    gemmp_kernel<EPI_MLP2><<<nwg, 512, 0, stream>>>(g, Wm2T, b_mlp2, d_out, x1, M, 384, 1536, nbn, nwg / 8);
  }
}

// Round 16
// 922.226 us; speedup vs baseline: 42.2658x; 42.2658x over previous
//
#include <hip/hip_runtime.h>
#include <math.h>

typedef __bf16 bf16x8 __attribute__((ext_vector_type(8)));
typedef float  f32x4  __attribute__((ext_vector_type(4)));
typedef _Float16 f16x2 __attribute__((ext_vector_type(2)));

__device__ __forceinline__ ushort f2bf(float f) {
  union { float f; unsigned u; } v; v.f = f;
  unsigned r = v.u + 0x7FFFu + ((v.u >> 16) & 1u);
  return (ushort)(r >> 16);
}
__device__ __forceinline__ float bf2f(ushort s) {
  union { unsigned u; float f; } v; v.u = ((unsigned)s) << 16;
  return v.f;
}
__device__ __forceinline__ unsigned pkrtz(float a, float b) {
  return __builtin_bit_cast(unsigned, __builtin_amdgcn_cvt_pkrtz(a, b));
}
__device__ __forceinline__ float fdot2(unsigned a, unsigned b, float c) {
  return __builtin_amdgcn_fdot2(__builtin_bit_cast(f16x2, a),
                                __builtin_bit_cast(f16x2, b), c, false);
}

__device__ __forceinline__ void gload_lds16(const ushort* g, ushort* l) {
  __builtin_amdgcn_global_load_lds((const __attribute__((address_space(1))) void*)g,
                                   (__attribute__((address_space(3))) void*)l, 16, 0, 0);
}

// fast GELU: h * sigmoid(1.5957691*h*(1+0.044715*h^2)), sigmoid via v_rcp
__device__ __forceinline__ float gelu_fast(float h) {
  float y = 1.5957691216057308f * h * (1.f + 0.044715f * h * h);
  return h * __builtin_amdgcn_rcpf(1.f + __expf(-y));
}

// ---------------- all 4 weight transposes in one launch ----------------
__global__ void wtrans_all(const float* __restrict__ W0, ushort* __restrict__ T0,
                           const float* __restrict__ W1, ushort* __restrict__ T1,
                           const float* __restrict__ W2, ushort* __restrict__ T2,
                           const float* __restrict__ W3, ushort* __restrict__ T3) {
  int idx = blockIdx.x * 256 + threadIdx.x;
  const float* W; ushort* T; int K, N, rel;
  if (idx < 442368)        { W = W0; T = T0; K = 384;  N = 1152; rel = idx; }
  else if (idx < 589824)   { W = W1; T = T1; K = 384;  N = 384;  rel = idx - 442368; }
  else if (idx < 1179648)  { W = W2; T = T2; K = 384;  N = 1536; rel = idx - 589824; }
  else                     { W = W3; T = T3; K = 1536; N = 384;  rel = idx - 1179648; }
  int n = rel / K, k = rel - n * K;
  T[rel] = f2bf(W[(size_t)k * N + n]);
}

// ---------------- LayerNorm (one wave per row of 384), paired loads/stores ----------------
template<bool SHIFT, bool INBF16>
__global__ __launch_bounds__(256) void ln_kernel(const void* __restrict__ inp,
                                                 ushort* __restrict__ outp,
                                                 const float* __restrict__ gamma,
                                                 const float* __restrict__ beta) {
  const int lane = threadIdx.x & 63;
  const int row = blockIdx.x * 4 + (threadIdx.x >> 6);
  size_t src;
  if (SHIFT) {
    int b = row / 3136, rem = row - b * 3136;
    int win = rem / 49, n = rem - win * 49;
    int wh = win >> 3, ww = win & 7;
    int i = n / 7, j = n - (n / 7) * 7;
    int h = wh * 7 + i + 3; if (h >= 56) h -= 56;
    int w = ww * 7 + j + 3; if (w >= 56) w -= 56;
    src = ((size_t)b * 3136 + h * 56 + w) * 384;
  } else {
    src = (size_t)row * 384;
  }
  float2 xv[3];
  float sum = 0.f, sq = 0.f;
#pragma unroll
  for (int t = 0; t < 3; t++) {
    int c = (lane + t * 64) * 2;
    float2 f;
    if (INBF16) {
      unsigned u = *(const unsigned*)((const ushort*)inp + src + c);
      f.x = bf2f((ushort)(u & 0xFFFF));
      f.y = bf2f((ushort)(u >> 16));
    } else {
      f = *(const float2*)((const float*)inp + src + c);
    }
    xv[t] = f; sum += f.x + f.y; sq += f.x * f.x + f.y * f.y;
  }
#pragma unroll
  for (int o = 32; o; o >>= 1) { sum += __shfl_xor(sum, o); sq += __shfl_xor(sq, o); }
  float mean = sum * (1.f / 384.f);
  float var  = sq * (1.f / 384.f) - mean * mean;
  float inv  = rsqrtf(var + 1e-5f);
#pragma unroll
  for (int t = 0; t < 3; t++) {
    int c = (lane + t * 64) * 2;
    float2 g = *(const float2*)(gamma + c);
    float2 b = *(const float2*)(beta + c);
    ushort2 o;
    o.x = f2bf((xv[t].x - mean) * inv * g.x + b.x);
    o.y = f2bf((xv[t].y - mean) * inv * g.y + b.y);
    *(ushort2*)(outp + (size_t)row * 384 + c) = o;
  }
}

#define EPI_QKV  0
#define EPI_PROJ 1
#define EPI_MLP1 2
#define EPI_MLP2 3

// ---------------- pipelined GEMM: 128x128 block, 8 waves x 64x32, BK=32 ----------------
// 4-buffer LDS (64KB, 2 blocks/CU), depth-3 staging with counted vmcnt(2), register
// double-buffered fragments with NAMED sets (hand-unrolled x2 -> all reg indices
// compile-time constant; rule-#20-safe). MFMA cluster never waits on fresh ds_reads.
template<int EPI>
__global__ __launch_bounds__(512, 4) void gemmp_kernel(
    const ushort* __restrict__ A, const ushort* __restrict__ BT,
    const float* __restrict__ bias, void* __restrict__ Cout,
    const void* __restrict__ extra, int M, int N, int K, int nbn, int cpx) {
  __shared__ ushort SH[32768];   // A: 4x4096, B (at 16384): 4x4096; epi scratch reuse
  const int tid = threadIdx.x;
  const int flat = blockIdx.x;
  const int wg = (flat & 7) * cpx + (flat >> 3);   // bijective XCD swizzle (nwg%8==0)
  const int bm = wg / nbn, bn = wg - bm * nbn;
  const int m0 = bm * 128, n0 = bn * 128;
  const int lane = tid & 63, wave = tid >> 6;      // 8 waves
  const int wr = (wave >> 2) * 64, wc = (wave & 3) * 32;
  const int fr = lane & 15, fq = lane >> 4;
  const int key = (fr >> 1) & 3;
  f32x4 acc[4][2] = {};

  const int r8 = lane >> 2;                        // row 0..15 within 16-row chunk
  const int sslot = ((lane & 3) ^ ((lane >> 3) & 3)) * 8;
  const size_t a_base = (size_t)(m0 + wave * 16 + r8) * K + sslot;
  const size_t b_base = (size_t)(n0 + wave * 16 + r8) * K + sslot;

#define STAGE(c, kt_) do {                                         \
    gload_lds16(A  + a_base + (kt_), SH + (c) * 4096 + wave * 512);           \
    gload_lds16(BT + b_base + (kt_), SH + 16384 + (c) * 4096 + wave * 512);   \
  } while (0)

#define LOADF(FA, FB, c) do {                                      \
    _Pragma("unroll")                                              \
    for (int i = 0; i < 4; i++) {                                  \
      int ra = wr + i * 16 + fr;                                   \
      FA[i] = *(const bf16x8*)&SH[(c) * 4096 + ra * 32 + ((fq ^ key) * 8)]; \
    }                                                              \
    _Pragma("unroll")                                              \
    for (int j = 0; j < 2; j++) {                                  \
      int rb = wc + j * 16 + fr;                                   \
      FB[j] = *(const bf16x8*)&SH[16384 + (c) * 4096 + rb * 32 + ((fq ^ key) * 8)]; \
    }                                                              \
  } while (0)

#define MFMA8(FA, FB) do {                                         \
    _Pragma("unroll")                                              \
    for (int i = 0; i < 4; i++)                                    \
      _Pragma("unroll")                                            \
      for (int j = 0; j < 2; j++)                                  \
        acc[i][j] = __builtin_amdgcn_mfma_f32_16x16x32_bf16(FA[i], FB[j], acc[i][j], 0, 0, 0); \
  } while (0)

  const int NT = K >> 5;   // 12 (K=384) or 48 (K=1536) -- always even
  STAGE(0, 0);
  STAGE(1, 32);
  STAGE(2, 64);
  asm volatile("s_waitcnt vmcnt(2) lgkmcnt(0)" ::: "memory");   // tiles 0,1 complete
  __builtin_amdgcn_s_barrier();
  __builtin_amdgcn_sched_barrier(0);

  bf16x8 faA[4], fbA[2], faB[4], fbB[2];
  LOADF(faA, fbA, 0);
  for (int t = 0; t < NT; t += 2) {
    // ---- even iter: compute tile t (regs A); prefetch tile t+1 -> regs B
    if (t + 3 < NT) STAGE((t + 3) & 3, (t + 3) * 32);
    if (t + 1 < NT) LOADF(faB, fbB, (t + 1) & 3);
    __builtin_amdgcn_sched_barrier(0);
    __builtin_amdgcn_s_setprio(1);
    MFMA8(faA, fbA);
    __builtin_amdgcn_s_setprio(0);
    if (t + 1 < NT) {
      if (t + 3 < NT) asm volatile("s_waitcnt vmcnt(2)" ::: "memory");
      else            asm volatile("s_waitcnt vmcnt(0)" ::: "memory");
      __builtin_amdgcn_s_barrier();
      __builtin_amdgcn_sched_barrier(0);
    }
    // ---- odd iter: compute tile t+1 (regs B); prefetch tile t+2 -> regs A
    if (t + 4 < NT) STAGE((t + 4) & 3, (t + 4) * 32);
    if (t + 2 < NT) LOADF(faA, fbA, (t + 2) & 3);
    __builtin_amdgcn_sched_barrier(0);
    __builtin_amdgcn_s_setprio(1);
    MFMA8(faB, fbB);
    __builtin_amdgcn_s_setprio(0);
    if (t + 2 < NT) {
      if (t + 4 < NT) asm volatile("s_waitcnt vmcnt(2)" ::: "memory");
      else            asm volatile("s_waitcnt vmcnt(0)" ::: "memory");
      __builtin_amdgcn_s_barrier();
      __builtin_amdgcn_sched_barrier(0);
    }
  }
#undef STAGE
#undef LOADF
#undef MFMA8

  __syncthreads();
  float biasv[2];
#pragma unroll
  for (int j = 0; j < 2; j++) biasv[j] = bias[n0 + wc + j * 16 + fr];

  if constexpr (EPI == EPI_MLP2) {
    float* scr = (float*)SH + wave * 1152;
#pragma unroll
    for (int c = 0; c < 2; c++) {
#pragma unroll
      for (int i = 0; i < 2; i++)
#pragma unroll
        for (int j = 0; j < 2; j++)
#pragma unroll
          for (int r = 0; r < 4; r++)
            scr[(i * 16 + fq * 4 + r) * 36 + j * 16 + fr] = acc[c * 2 + i][j][r] + biasv[j];
      asm volatile("" ::: "memory");
#pragma unroll
      for (int it = 0; it < 4; it++) {
        int row = it * 8 + (lane >> 3);
        f32x4 v = *(const f32x4*)&scr[row * 36 + (lane & 7) * 4];
        int m = m0 + wr + c * 32 + row;
        int col0 = n0 + wc + (lane & 7) * 4;
        ushort4 xv = *(const ushort4*)((const ushort*)extra + (size_t)m * N + col0);
        v[0] += bf2f(xv.x); v[1] += bf2f(xv.y); v[2] += bf2f(xv.z); v[3] += bf2f(xv.w);
        *(f32x4*)((float*)Cout + (size_t)m * N + col0) = v;
      }
      asm volatile("" ::: "memory");
    }
  } else {
    ushort* scr = SH + wave * 2304;
#pragma unroll
    for (int i = 0; i < 4; i++)
#pragma unroll
      for (int j = 0; j < 2; j++)
#pragma unroll
        for (int r = 0; r < 4; r++) {
          float val = acc[i][j][r] + biasv[j];
          if constexpr (EPI == EPI_MLP1) val = gelu_fast(val);
          scr[(i * 16 + fq * 4 + r) * 36 + j * 16 + fr] = f2bf(val);
        }
    asm volatile("" ::: "memory");
#pragma unroll
    for (int it = 0; it < 4; it++) {
      int row = it * 16 + (lane >> 2);
      int m = m0 + wr + row;
      int col0 = n0 + wc + (lane & 3) * 8;
      ushort v[8];
      *(bf16x8*)v = *(const bf16x8*)&scr[row * 36 + (lane & 3) * 8];
      if constexpr (EPI == EPI_PROJ) {
        int b_ = m / 3136, rem = m - b_ * 3136;
        int win = rem / 49, nn = rem - win * 49;
        int wh = win >> 3, ww = win & 7;
        int ii = nn / 7, jj = nn - (nn / 7) * 7;
        int h = wh * 7 + ii + 3; if (h >= 56) h -= 56;
        int w = ww * 7 + jj + 3; if (w >= 56) w -= 56;
        size_t rowbase = ((size_t)b_ * 3136 + h * 56 + w) * 384;
        const float* e = (const float*)extra + rowbase + col0;
        ushort o[8];
#pragma unroll
        for (int k = 0; k < 8; k++) o[k] = f2bf(bf2f(v[k]) + e[k]);
        *(bf16x8*)((ushort*)Cout + rowbase + col0) = *(bf16x8*)o;
      } else {
        *(bf16x8*)((ushort*)Cout + (size_t)m * N + col0) = *(bf16x8*)v;
      }
    }
  }
}

// ---------------- windowed attention: streaming softmax, f16 dot2 math ----------------
__global__ __launch_bounds__(128) void attn_kernel(
    const ushort* __restrict__ qkv, const float* __restrict__ bias_table,
    ushort* __restrict__ outp) {
  __shared__ unsigned k_lds[2][49][16];
  __shared__ unsigned v_lds[2][32][28];
  __shared__ float btab[2][169];
  __shared__ char  rgn[2][52];
  const int wave = threadIdx.x >> 6, lane = threadIdx.x & 63;
  const int gw = blockIdx.x * 2 + wave;
  const int bw = gw / 12, head = gw - bw * 12;
  const ushort* base = qkv + (size_t)bw * 49 * 1152 + head * 32;

  for (int t = lane; t < 392; t += 64) {
    int m = t >> 3, c4 = t & 7;
    ushort4 u = *(const ushort4*)(base + (size_t)m * 1152 + 384 + c4 * 4);
    *(uint2*)&k_lds[wave][m][c4 * 2] =
        make_uint2(pkrtz(bf2f(u.x), bf2f(u.y)), pkrtz(bf2f(u.z), bf2f(u.w)));
  }
  for (int t = lane; t < 224; t += 64) {
    int m2 = t >> 3, c4 = t & 7;
    float4 f0 = make_float4(0.f, 0.f, 0.f, 0.f), f1 = f0;
    if (m2 <= 24) {
      ushort4 u = *(const ushort4*)(base + (size_t)(2 * m2) * 1152 + 768 + c4 * 4);
      f0 = make_float4(bf2f(u.x), bf2f(u.y), bf2f(u.z), bf2f(u.w));
    }
    if (m2 <= 23) {
      ushort4 u = *(const ushort4*)(base + (size_t)(2 * m2 + 1) * 1152 + 768 + c4 * 4);
      f1 = make_float4(bf2f(u.x), bf2f(u.y), bf2f(u.z), bf2f(u.w));
    }
    v_lds[wave][c4 * 4 + 0][m2] = pkrtz(f0.x, f1.x);
    v_lds[wave][c4 * 4 + 1][m2] = pkrtz(f0.y, f1.y);
    v_lds[wave][c4 * 4 + 2][m2] = pkrtz(f0.z, f1.z);
    v_lds[wave][c4 * 4 + 3][m2] = pkrtz(f0.w, f1.w);
  }
  for (int t = lane; t < 169; t += 64) btab[wave][t] = bias_table[t * 12 + head];
  {
    int win = bw & 63, wh = win >> 3, ww = win & 7;
    if (lane < 49) {
      int i = lane / 7, j = lane - (lane / 7) * 7;
      int hs = wh * 7 + i, wsf = ww * 7 + j;
      int bh = (hs < 49) ? 0 : (hs < 53 ? 1 : 2);
      int bv = (wsf < 49) ? 0 : (wsf < 53 ? 1 : 2);
      rgn[wave][lane] = (char)(bh * 3 + bv);
    }
  }
  __syncthreads();

  const int n = (lane < 49) ? lane : 48;
  unsigned q2[16];
  {
    const ushort* qp = base + (size_t)n * 1152;
#pragma unroll
    for (int t = 0; t < 8; t++) {
      ushort4 u = *(const ushort4*)(qp + t * 4);
      const float sc = 0.17677669529663689f;
      q2[2 * t]     = pkrtz(bf2f(u.x) * sc, bf2f(u.y) * sc);
      q2[2 * t + 1] = pkrtz(bf2f(u.z) * sc, bf2f(u.w) * sc);
    }
  }
  const char rn = rgn[wave][n];
  const int i_n = n / 7, j_n = n - (n / 7) * 7;
  const float* bt = &btab[wave][(i_n + 6) * 13 + (j_n + 6)];

  auto qk_one = [&](int m) -> float {
    const uint4* kr = (const uint4*)&k_lds[wave][m][0];
    uint4 k0 = kr[0], k1 = kr[1], k2 = kr[2], k3 = kr[3];
    float a0 = 0.f, a1 = 0.f, a2 = 0.f, a3 = 0.f;
    a0 = fdot2(k0.x, q2[0],  a0); a1 = fdot2(k0.y, q2[1],  a1);
    a2 = fdot2(k0.z, q2[2],  a2); a3 = fdot2(k0.w, q2[3],  a3);
    a0 = fdot2(k1.x, q2[4],  a0); a1 = fdot2(k1.y, q2[5],  a1);
    a2 = fdot2(k1.z, q2[6],  a2); a3 = fdot2(k1.w, q2[7],  a3);
    a0 = fdot2(k2.x, q2[8],  a0); a1 = fdot2(k2.y, q2[9],  a1);
    a2 = fdot2(k2.z, q2[10], a2); a3 = fdot2(k2.w, q2[11], a3);
    a0 = fdot2(k3.x, q2[12], a0); a1 = fdot2(k3.y, q2[13], a1);
    a2 = fdot2(k3.z, q2[14], a2); a3 = fdot2(k3.w, q2[15], a3);
    int im = m / 7, jm = m - (m / 7) * 7;
    float s = (a0 + a1) + (a2 + a3) + bt[-im * 13 - jm];
    s += (rgn[wave][m] == rn) ? 0.f : -100.f;
    return __expf(s);
  };

  float sum = 0.f;
  unsigned p2[28];
#pragma unroll
  for (int m2 = 0; m2 < 25; m2++) {
    float eA = qk_one(2 * m2);
    float eB = (m2 < 24) ? qk_one(2 * m2 + 1) : 0.f;
    sum += eA + eB;
    p2[m2] = pkrtz(eA, eB);
  }
  p2[25] = 0; p2[26] = 0; p2[27] = 0;

  const float invs = __builtin_amdgcn_rcpf(sum);
  ushort* op = outp + (size_t)(bw * 49 + n) * 384 + head * 32;
#pragma unroll
  for (int dc = 0; dc < 4; dc++) {
    ushort u8[8];
#pragma unroll
    for (int j = 0; j < 8; j++) {
      const uint4* vr = (const uint4*)&v_lds[wave][dc * 8 + j][0];
      float a0 = 0.f, a1 = 0.f, a2 = 0.f, a3 = 0.f;
#pragma unroll
      for (int t7 = 0; t7 < 7; t7++) {
        uint4 vv = vr[t7];
        a0 = fdot2(vv.x, p2[t7 * 4 + 0], a0);
        a1 = fdot2(vv.y, p2[t7 * 4 + 1], a1);
        a2 = fdot2(vv.z, p2[t7 * 4 + 2], a2);
        a3 = fdot2(vv.w, p2[t7 * 4 + 3], a3);
      }
      u8[j] = f2bf(((a0 + a1) + (a2 + a3)) * invs);
    }
    if (lane < 49) *(bf16x8*)(op + dc * 8) = *(bf16x8*)u8;
  }
}

extern "C" void kernel_launch(void* const* d_in, const int* in_sizes, int n_in,
                              void* d_out, int out_size, void* d_ws, size_t ws_size,
                              hipStream_t stream) {
  (void)in_sizes; (void)n_in; (void)out_size; (void)ws_size;
  const float* x      = (const float*)d_in[0];
  const float* W_qkv  = (const float*)d_in[1];
  const float* b_qkv  = (const float*)d_in[2];
  const float* W_proj = (const float*)d_in[3];
  const float* b_proj = (const float*)d_in[4];
  const float* btab   = (const float*)d_in[5];
  const float* gamma1 = (const float*)d_in[6];
  const float* beta1  = (const float*)d_in[7];
  const float* gamma2 = (const float*)d_in[8];
  const float* beta2  = (const float*)d_in[9];
  const float* W_mlp1 = (const float*)d_in[10];
  const float* b_mlp1 = (const float*)d_in[11];
  const float* W_mlp2 = (const float*)d_in[12];
  const float* b_mlp2 = (const float*)d_in[13];

  const int M = 100352;  // 32 * 3136 token rows

  char* ws = (char*)d_ws;
  ushort* WqkvT  = (ushort*)ws; ws += (size_t)1152 * 384 * 2;
  ushort* WprojT = (ushort*)ws; ws += (size_t)384 * 384 * 2;
  ushort* Wm1T   = (ushort*)ws; ws += (size_t)1536 * 384 * 2;
  ushort* Wm2T   = (ushort*)ws; ws += (size_t)384 * 1536 * 2;
  ushort* x1     = (ushort*)ws; ws += (size_t)M * 384 * 2;   // bf16 residual trunk
  ushort* h2     = (ushort*)ws; ws += (size_t)M * 384 * 2;
  ushort* bufB   = (ushort*)ws;                               // overlay region
  ushort* xw     = bufB;                                      // [M][384]
  ushort* qkv    = bufB + (size_t)M * 384;                    // [M][1152]
  ushort* attn_o = bufB;                                      // [M][384]  (over xw)
  ushort* g      = bufB;                                      // [M][1536] (over all)

  wtrans_all<<<6912, 256, 0, stream>>>(W_qkv, WqkvT, W_proj, WprojT,
                                       W_mlp1, Wm1T, W_mlp2, Wm2T);

  ln_kernel<true,  false><<<M / 4, 256, 0, stream>>>(x, xw, gamma1, beta1);

  {
    int nbn = 1152 / 128, nwg = (M / 128) * nbn;
    gemmp_kernel<EPI_QKV ><<<nwg, 512, 0, stream>>>(xw, WqkvT, b_qkv, qkv, nullptr, M, 1152, 384, nbn, nwg / 8);
  }
  attn_kernel<<<12288, 128, 0, stream>>>(qkv, btab, attn_o);
  {
    int nbn = 384 / 128, nwg = (M / 128) * nbn;
    gemmp_kernel<EPI_PROJ><<<nwg, 512, 0, stream>>>(attn_o, WprojT, b_proj, x1, x, M, 384, 384, nbn, nwg / 8);
  }
  ln_kernel<false, true><<<M / 4, 256, 0, stream>>>(x1, h2, gamma2, beta2);
  {
    int nbn = 1536 / 128, nwg = (M / 128) * nbn;
    gemmp_kernel<EPI_MLP1><<<nwg, 512, 0, stream>>>(h2, Wm1T, b_mlp1, g, nullptr, M, 1536, 384, nbn, nwg / 8);
  }
  {
    int nbn = 384 / 128, nwg = (M / 128) * nbn;
    gemmp_kernel<EPI_MLP2><<<nwg, 512, 0, stream>>>(g, Wm2T, b_mlp2, d_out, x1, M, 384, 1536, nbn, nwg / 8);
  }
}

// Round 17
// 847.469 us; speedup vs baseline: 45.9942x; 1.0882x over previous
//
#include <hip/hip_runtime.h>
#include <math.h>

typedef __bf16 bf16x8 __attribute__((ext_vector_type(8)));
typedef float  f32x4  __attribute__((ext_vector_type(4)));
typedef _Float16 f16x2 __attribute__((ext_vector_type(2)));

__device__ __forceinline__ ushort f2bf(float f) {
  union { float f; unsigned u; } v; v.f = f;
  unsigned r = v.u + 0x7FFFu + ((v.u >> 16) & 1u);
  return (ushort)(r >> 16);
}
__device__ __forceinline__ float bf2f(ushort s) {
  union { unsigned u; float f; } v; v.u = ((unsigned)s) << 16;
  return v.f;
}
__device__ __forceinline__ unsigned pkrtz(float a, float b) {
  return __builtin_bit_cast(unsigned, __builtin_amdgcn_cvt_pkrtz(a, b));
}
__device__ __forceinline__ float fdot2(unsigned a, unsigned b, float c) {
  return __builtin_amdgcn_fdot2(__builtin_bit_cast(f16x2, a),
                                __builtin_bit_cast(f16x2, b), c, false);
}

__device__ __forceinline__ void gload_lds16(const ushort* g, ushort* l) {
  __builtin_amdgcn_global_load_lds((const __attribute__((address_space(1))) void*)g,
                                   (__attribute__((address_space(3))) void*)l, 16, 0, 0);
}

// fast GELU: h * sigmoid(1.5957691*h*(1+0.044715*h^2)), sigmoid via v_rcp
__device__ __forceinline__ float gelu_fast(float h) {
  float y = 1.5957691216057308f * h * (1.f + 0.044715f * h * h);
  return h * __builtin_amdgcn_rcpf(1.f + __expf(-y));
}

// ---------------- weight transpose + bf16 convert: W[K][N] -> WT[N][K] ----------------
__global__ void wtrans_kernel(const float* __restrict__ W, ushort* __restrict__ WT,
                              int K, int N) {
  int idx = blockIdx.x * 256 + threadIdx.x;
  if (idx >= K * N) return;
  int n = idx / K, k = idx - n * K;
  WT[idx] = f2bf(W[(size_t)k * N + n]);
}

// ---------------- LayerNorm (one wave per row of 384), paired loads/stores ----------------
template<bool SHIFT, bool INBF16>
__global__ __launch_bounds__(256) void ln_kernel(const void* __restrict__ inp,
                                                 ushort* __restrict__ outp,
                                                 const float* __restrict__ gamma,
                                                 const float* __restrict__ beta) {
  const int lane = threadIdx.x & 63;
  const int row = blockIdx.x * 4 + (threadIdx.x >> 6);
  size_t src;
  if (SHIFT) {
    int b = row / 3136, rem = row - b * 3136;
    int win = rem / 49, n = rem - win * 49;
    int wh = win >> 3, ww = win & 7;
    int i = n / 7, j = n - (n / 7) * 7;
    int h = wh * 7 + i + 3; if (h >= 56) h -= 56;
    int w = ww * 7 + j + 3; if (w >= 56) w -= 56;
    src = ((size_t)b * 3136 + h * 56 + w) * 384;
  } else {
    src = (size_t)row * 384;
  }
  float2 xv[3];
  float sum = 0.f, sq = 0.f;
#pragma unroll
  for (int t = 0; t < 3; t++) {
    int c = (lane + t * 64) * 2;
    float2 f;
    if (INBF16) {
      unsigned u = *(const unsigned*)((const ushort*)inp + src + c);
      f.x = bf2f((ushort)(u & 0xFFFF));
      f.y = bf2f((ushort)(u >> 16));
    } else {
      f = *(const float2*)((const float*)inp + src + c);
    }
    xv[t] = f; sum += f.x + f.y; sq += f.x * f.x + f.y * f.y;
  }
#pragma unroll
  for (int o = 32; o; o >>= 1) { sum += __shfl_xor(sum, o); sq += __shfl_xor(sq, o); }
  float mean = sum * (1.f / 384.f);
  float var  = sq * (1.f / 384.f) - mean * mean;
  float inv  = rsqrtf(var + 1e-5f);
#pragma unroll
  for (int t = 0; t < 3; t++) {
    int c = (lane + t * 64) * 2;
    float2 g = *(const float2*)(gamma + c);
    float2 b = *(const float2*)(beta + c);
    ushort2 o;
    o.x = f2bf((xv[t].x - mean) * inv * g.x + b.x);
    o.y = f2bf((xv[t].y - mean) * inv * g.y + b.y);
    *(ushort2*)(outp + (size_t)row * 384 + c) = o;
  }
}

// ---------------- bf16 MFMA GEMM: C[M][N] = A[M][K] * BT[N][K]^T + bias ----------------
// 256x128 block, 8 waves x (64x64 wave tile), BK=32, 3-buffer LDS (72KB -> 2 blocks/CU),
// 2-deep prefetch, counted vmcnt(3), raw s_barrier, XOR-swizzle key (row>>1)&3,
// setprio around MFMA cluster, vectorized epilogue via per-wave LDS scratch.
#define EPI_QKV  0
#define EPI_PROJ 1
#define EPI_MLP1 2
#define EPI_MLP2 3

template<int EPI>
__global__ __launch_bounds__(512, 4) void gemm_kernel(
    const ushort* __restrict__ A, const ushort* __restrict__ BT,
    const float* __restrict__ bias, void* __restrict__ Cout,
    const void* __restrict__ extra, int M, int N, int K, int nbn, int cpx) {
  __shared__ ushort SH[36864];   // A: 3x8192, B (at 24576): 3x4096; epi scratch reuse
  const int tid = threadIdx.x;
  const int flat = blockIdx.x;
  const int wg = (flat & 7) * cpx + (flat >> 3);   // bijective XCD swizzle (nwg%8==0)
  const int bm = wg / nbn, bn = wg - bm * nbn;
  const int m0 = bm * 256, n0 = bn * 128;
  const int lane = tid & 63, wave = tid >> 6;      // 8 waves
  const int wr = (wave >> 1) * 64, wc = (wave & 1) * 64;
  const int fr = lane & 15, fq = lane >> 4;
  const int key = (fr >> 1) & 3;                   // read-side swizzle key (lane-const)
  f32x4 acc[4][4] = {};

  const int r16 = lane >> 2;
  const int sslot = ((lane & 3) ^ ((lane >> 3) & 3)) * 8;
  const size_t a_base = (size_t)(m0 + wave * 32 + r16) * K + sslot;
  const size_t b_base = (size_t)(n0 + wave * 16 + r16) * K + sslot;

#define STAGE(c, kt_) do {                                                     \
    gload_lds16(A  + a_base + (kt_),          SH + (c) * 8192 + wave * 1024);  \
    gload_lds16(A  + a_base + 16 * K + (kt_), SH + (c) * 8192 + wave * 1024 + 512); \
    gload_lds16(BT + b_base + (kt_),          SH + 24576 + (c) * 4096 + wave * 512); \
  } while (0)

  const int NT = K >> 5;
  STAGE(0, 0);
  STAGE(1, 32);
  asm volatile("s_waitcnt vmcnt(3) lgkmcnt(0)" ::: "memory");
  __builtin_amdgcn_s_barrier();
  __builtin_amdgcn_sched_barrier(0);

  int cur = 0;
  for (int t = 0; t < NT; ++t) {
    if (t + 2 < NT) {
      int nx = cur + 2; if (nx >= 3) nx -= 3;
      STAGE(nx, (t + 2) * 32);
    }
    bf16x8 a[4], b[4];
#pragma unroll
    for (int i = 0; i < 4; i++) {
      int ra = wr + i * 16 + fr;
      a[i] = *(const bf16x8*)&SH[cur * 8192 + ra * 32 + ((fq ^ key) * 8)];
    }
#pragma unroll
    for (int j = 0; j < 4; j++) {
      int rb = wc + j * 16 + fr;
      b[j] = *(const bf16x8*)&SH[24576 + cur * 4096 + rb * 32 + ((fq ^ key) * 8)];
    }
    __builtin_amdgcn_s_setprio(1);
#pragma unroll
    for (int i = 0; i < 4; i++)
#pragma unroll
      for (int j = 0; j < 4; j++)
        acc[i][j] = __builtin_amdgcn_mfma_f32_16x16x32_bf16(a[i], b[j], acc[i][j], 0, 0, 0);
    __builtin_amdgcn_s_setprio(0);
    if (t + 1 < NT) {
      if (t + 2 < NT) asm volatile("s_waitcnt vmcnt(3) lgkmcnt(0)" ::: "memory");
      else            asm volatile("s_waitcnt vmcnt(0) lgkmcnt(0)" ::: "memory");
      __builtin_amdgcn_s_barrier();
      __builtin_amdgcn_sched_barrier(0);
      cur += 1; if (cur >= 3) cur -= 3;
    }
  }
#undef STAGE

  __syncthreads();
  float biasv[4];
#pragma unroll
  for (int j = 0; j < 4; j++) biasv[j] = bias[n0 + wc + j * 16 + fr];

  if constexpr (EPI == EPI_MLP2) {
    float* scr = (float*)SH + wave * 2112;
#pragma unroll
    for (int c = 0; c < 2; c++) {
#pragma unroll
      for (int i = 0; i < 2; i++)
#pragma unroll
        for (int j = 0; j < 4; j++)
#pragma unroll
          for (int r = 0; r < 4; r++)
            scr[(i * 16 + fq * 4 + r) * 66 + j * 16 + fr] = acc[c * 2 + i][j][r] + biasv[j];
      asm volatile("" ::: "memory");
#pragma unroll
      for (int it = 0; it < 8; it++) {
        int row = it * 4 + (lane >> 4);
        f32x4 v = *(const f32x4*)&scr[row * 66 + (lane & 15) * 4];
        int m = m0 + wr + c * 32 + row;
        int col0 = n0 + wc + (lane & 15) * 4;
        ushort4 xv = *(const ushort4*)((const ushort*)extra + (size_t)m * N + col0);
        v[0] += bf2f(xv.x); v[1] += bf2f(xv.y); v[2] += bf2f(xv.z); v[3] += bf2f(xv.w);
        *(f32x4*)((float*)Cout + (size_t)m * N + col0) = v;
      }
      asm volatile("" ::: "memory");
    }
  } else {
    ushort* scr = SH + wave * 4352;
#pragma unroll
    for (int i = 0; i < 4; i++)
#pragma unroll
      for (int j = 0; j < 4; j++)
#pragma unroll
        for (int r = 0; r < 4; r++) {
          float val = acc[i][j][r] + biasv[j];
          if constexpr (EPI == EPI_MLP1) val = gelu_fast(val);
          scr[(i * 16 + fq * 4 + r) * 68 + j * 16 + fr] = f2bf(val);
        }
    asm volatile("" ::: "memory");
#pragma unroll
    for (int it = 0; it < 8; it++) {
      int row = it * 8 + (lane >> 3);
      int m = m0 + wr + row;
      int col0 = n0 + wc + (lane & 7) * 8;
      ushort v[8];
      *(bf16x8*)v = *(const bf16x8*)&scr[row * 68 + (lane & 7) * 8];
      if constexpr (EPI == EPI_PROJ) {
        int b_ = m / 3136, rem = m - b_ * 3136;
        int win = rem / 49, nn = rem - win * 49;
        int wh = win >> 3, ww = win & 7;
        int ii = nn / 7, jj = nn - (nn / 7) * 7;
        int h = wh * 7 + ii + 3; if (h >= 56) h -= 56;
        int w = ww * 7 + jj + 3; if (w >= 56) w -= 56;
        size_t rowbase = ((size_t)b_ * 3136 + h * 56 + w) * 384;
        const float* e = (const float*)extra + rowbase + col0;
        ushort o[8];
#pragma unroll
        for (int k = 0; k < 8; k++) o[k] = f2bf(bf2f(v[k]) + e[k]);
        *(bf16x8*)((ushort*)Cout + rowbase + col0) = *(bf16x8*)o;
      } else {
        *(bf16x8*)((ushort*)Cout + (size_t)m * N + col0) = *(bf16x8*)v;
      }
    }
  }
}

// ---------------- windowed attention: streaming softmax, f16 dot2 math ----------------
__global__ __launch_bounds__(128) void attn_kernel(
    const ushort* __restrict__ qkv, const float* __restrict__ bias_table,
    ushort* __restrict__ outp) {
  __shared__ unsigned k_lds[2][49][16];
  __shared__ unsigned v_lds[2][32][28];
  __shared__ float btab[2][169];
  __shared__ char  rgn[2][52];
  const int wave = threadIdx.x >> 6, lane = threadIdx.x & 63;
  const int gw = blockIdx.x * 2 + wave;
  const int bw = gw / 12, head = gw - bw * 12;
  const ushort* base = qkv + (size_t)bw * 49 * 1152 + head * 32;

  for (int t = lane; t < 392; t += 64) {
    int m = t >> 3, c4 = t & 7;
    ushort4 u = *(const ushort4*)(base + (size_t)m * 1152 + 384 + c4 * 4);
    *(uint2*)&k_lds[wave][m][c4 * 2] =
        make_uint2(pkrtz(bf2f(u.x), bf2f(u.y)), pkrtz(bf2f(u.z), bf2f(u.w)));
  }
  for (int t = lane; t < 224; t += 64) {
    int m2 = t >> 3, c4 = t & 7;
    float4 f0 = make_float4(0.f, 0.f, 0.f, 0.f), f1 = f0;
    if (m2 <= 24) {
      ushort4 u = *(const ushort4*)(base + (size_t)(2 * m2) * 1152 + 768 + c4 * 4);
      f0 = make_float4(bf2f(u.x), bf2f(u.y), bf2f(u.z), bf2f(u.w));
    }
    if (m2 <= 23) {
      ushort4 u = *(const ushort4*)(base + (size_t)(2 * m2 + 1) * 1152 + 768 + c4 * 4);
      f1 = make_float4(bf2f(u.x), bf2f(u.y), bf2f(u.z), bf2f(u.w));
    }
    v_lds[wave][c4 * 4 + 0][m2] = pkrtz(f0.x, f1.x);
    v_lds[wave][c4 * 4 + 1][m2] = pkrtz(f0.y, f1.y);
    v_lds[wave][c4 * 4 + 2][m2] = pkrtz(f0.z, f1.z);
    v_lds[wave][c4 * 4 + 3][m2] = pkrtz(f0.w, f1.w);
  }
  for (int t = lane; t < 169; t += 64) btab[wave][t] = bias_table[t * 12 + head];
  {
    int win = bw & 63, wh = win >> 3, ww = win & 7;
    if (lane < 49) {
      int i = lane / 7, j = lane - (lane / 7) * 7;
      int hs = wh * 7 + i, wsf = ww * 7 + j;
      int bh = (hs < 49) ? 0 : (hs < 53 ? 1 : 2);
      int bv = (wsf < 49) ? 0 : (wsf < 53 ? 1 : 2);
      rgn[wave][lane] = (char)(bh * 3 + bv);
    }
  }
  __syncthreads();

  const int n = (lane < 49) ? lane : 48;
  unsigned q2[16];
  {
    const ushort* qp = base + (size_t)n * 1152;
#pragma unroll
    for (int t = 0; t < 8; t++) {
      ushort4 u = *(const ushort4*)(qp + t * 4);
      const float sc = 0.17677669529663689f;
      q2[2 * t]     = pkrtz(bf2f(u.x) * sc, bf2f(u.y) * sc);
      q2[2 * t + 1] = pkrtz(bf2f(u.z) * sc, bf2f(u.w) * sc);
    }
  }
  const char rn = rgn[wave][n];
  const int i_n = n / 7, j_n = n - (n / 7) * 7;
  const float* bt = &btab[wave][(i_n + 6) * 13 + (j_n + 6)];

  auto qk_one = [&](int m) -> float {
    const uint4* kr = (const uint4*)&k_lds[wave][m][0];
    uint4 k0 = kr[0], k1 = kr[1], k2 = kr[2], k3 = kr[3];
    float a0 = 0.f, a1 = 0.f, a2 = 0.f, a3 = 0.f;
    a0 = fdot2(k0.x, q2[0],  a0); a1 = fdot2(k0.y, q2[1],  a1);
    a2 = fdot2(k0.z, q2[2],  a2); a3 = fdot2(k0.w, q2[3],  a3);
    a0 = fdot2(k1.x, q2[4],  a0); a1 = fdot2(k1.y, q2[5],  a1);
    a2 = fdot2(k1.z, q2[6],  a2); a3 = fdot2(k1.w, q2[7],  a3);
    a0 = fdot2(k2.x, q2[8],  a0); a1 = fdot2(k2.y, q2[9],  a1);
    a2 = fdot2(k2.z, q2[10], a2); a3 = fdot2(k2.w, q2[11], a3);
    a0 = fdot2(k3.x, q2[12], a0); a1 = fdot2(k3.y, q2[13], a1);
    a2 = fdot2(k3.z, q2[14], a2); a3 = fdot2(k3.w, q2[15], a3);
    int im = m / 7, jm = m - (m / 7) * 7;
    float s = (a0 + a1) + (a2 + a3) + bt[-im * 13 - jm];
    s += (rgn[wave][m] == rn) ? 0.f : -100.f;
    return __expf(s);
  };

  float sum = 0.f;
  unsigned p2[28];
#pragma unroll
  for (int m2 = 0; m2 < 25; m2++) {
    float eA = qk_one(2 * m2);
    float eB = (m2 < 24) ? qk_one(2 * m2 + 1) : 0.f;
    sum += eA + eB;
    p2[m2] = pkrtz(eA, eB);
  }
  p2[25] = 0; p2[26] = 0; p2[27] = 0;

  const float invs = __builtin_amdgcn_rcpf(sum);
  ushort* op = outp + (size_t)(bw * 49 + n) * 384 + head * 32;
#pragma unroll
  for (int dc = 0; dc < 4; dc++) {
    ushort u8[8];
#pragma unroll
    for (int j = 0; j < 8; j++) {
      const uint4* vr = (const uint4*)&v_lds[wave][dc * 8 + j][0];
      float a0 = 0.f, a1 = 0.f, a2 = 0.f, a3 = 0.f;
#pragma unroll
      for (int t7 = 0; t7 < 7; t7++) {
        uint4 vv = vr[t7];
        a0 = fdot2(vv.x, p2[t7 * 4 + 0], a0);
        a1 = fdot2(vv.y, p2[t7 * 4 + 1], a1);
        a2 = fdot2(vv.z, p2[t7 * 4 + 2], a2);
        a3 = fdot2(vv.w, p2[t7 * 4 + 3], a3);
      }
      u8[j] = f2bf(((a0 + a1) + (a2 + a3)) * invs);
    }
    if (lane < 49) *(bf16x8*)(op + dc * 8) = *(bf16x8*)u8;
  }
}

extern "C" void kernel_launch(void* const* d_in, const int* in_sizes, int n_in,
                              void* d_out, int out_size, void* d_ws, size_t ws_size,
                              hipStream_t stream) {
  (void)in_sizes; (void)n_in; (void)out_size; (void)ws_size;
  const float* x      = (const float*)d_in[0];
  const float* W_qkv  = (const float*)d_in[1];
  const float* b_qkv  = (const float*)d_in[2];
  const float* W_proj = (const float*)d_in[3];
  const float* b_proj = (const float*)d_in[4];
  const float* btab   = (const float*)d_in[5];
  const float* gamma1 = (const float*)d_in[6];
  const float* beta1  = (const float*)d_in[7];
  const float* gamma2 = (const float*)d_in[8];
  const float* beta2  = (const float*)d_in[9];
  const float* W_mlp1 = (const float*)d_in[10];
  const float* b_mlp1 = (const float*)d_in[11];
  const float* W_mlp2 = (const float*)d_in[12];
  const float* b_mlp2 = (const float*)d_in[13];

  const int M = 100352;  // 32 * 3136 token rows

  char* ws = (char*)d_ws;
  ushort* WqkvT  = (ushort*)ws; ws += (size_t)1152 * 384 * 2;
  ushort* WprojT = (ushort*)ws; ws += (size_t)384 * 384 * 2;
  ushort* Wm1T   = (ushort*)ws; ws += (size_t)1536 * 384 * 2;
  ushort* Wm2T   = (ushort*)ws; ws += (size_t)384 * 1536 * 2;
  ushort* x1     = (ushort*)ws; ws += (size_t)M * 384 * 2;   // bf16 residual trunk
  ushort* h2     = (ushort*)ws; ws += (size_t)M * 384 * 2;
  ushort* bufB   = (ushort*)ws;                               // overlay region
  ushort* xw     = bufB;                                      // [M][384]
  ushort* qkv    = bufB + (size_t)M * 384;                    // [M][1152]
  ushort* attn_o = bufB;                                      // [M][384]  (over xw)
  ushort* g      = bufB;                                      // [M][1536] (over all)

  wtrans_kernel<<<(384 * 1152 + 255) / 256, 256, 0, stream>>>(W_qkv,  WqkvT,  384, 1152);
  wtrans_kernel<<<(384 * 384  + 255) / 256, 256, 0, stream>>>(W_proj, WprojT, 384, 384);
  wtrans_kernel<<<(384 * 1536 + 255) / 256, 256, 0, stream>>>(W_mlp1, Wm1T,   384, 1536);
  wtrans_kernel<<<(1536 * 384 + 255) / 256, 256, 0, stream>>>(W_mlp2, Wm2T,   1536, 384);

  ln_kernel<true,  false><<<M / 4, 256, 0, stream>>>(x, xw, gamma1, beta1);

  {
    int nbn = 1152 / 128, nwg = (M / 256) * nbn;
    gemm_kernel<EPI_QKV ><<<nwg, 512, 0, stream>>>(xw, WqkvT, b_qkv, qkv, nullptr, M, 1152, 384, nbn, nwg / 8);
  }
  attn_kernel<<<12288, 128, 0, stream>>>(qkv, btab, attn_o);
  {
    int nbn = 384 / 128, nwg = (M / 256) * nbn;
    gemm_kernel<EPI_PROJ><<<nwg, 512, 0, stream>>>(attn_o, WprojT, b_proj, x1, x, M, 384, 384, nbn, nwg / 8);
  }
  ln_kernel<false, true><<<M / 4, 256, 0, stream>>>(x1, h2, gamma2, beta2);
  {
    int nbn = 1536 / 128, nwg = (M / 256) * nbn;
    gemm_kernel<EPI_MLP1><<<nwg, 512, 0, stream>>>(h2, Wm1T, b_mlp1, g, nullptr, M, 1536, 384, nbn, nwg / 8);
  }
  {
    int nbn = 384 / 128, nwg = (M / 256) * nbn;
    gemm_kernel<EPI_MLP2><<<nwg, 512, 0, stream>>>(g, Wm2T, b_mlp2, d_out, x1, M, 384, 1536, nbn, nwg / 8);
  }
}